// Round 1
// baseline (324.051 us; speedup 1.0000x reference)
//
#include <hip/hip_runtime.h>
#include <hip/hip_bf16.h>

typedef __bf16 bf16x8 __attribute__((ext_vector_type(8)));
typedef float f32x4 __attribute__((ext_vector_type(4)));
typedef unsigned short us4 __attribute__((ext_vector_type(4)));

#define TILE 128
#define APAD 136   // bf16 elems per LDS row: 128+8 keeps 16B align, even 8/bank b128 spread
#define OPAD 132   // f32 elems per LDS row for output restage (528B = 33*16, aligned)

__device__ __forceinline__ unsigned short f2bf(float f) {
    unsigned u = __float_as_uint(f);
    u += 0x7fffu + ((u >> 16) & 1u);   // round-to-nearest-even
    return (unsigned short)(u >> 16);
}
__device__ __forceinline__ float bf2f(unsigned short h) {
    return __uint_as_float(((unsigned)h) << 16);
}

__global__ __launch_bounds__(256, 2)
void rbf_mfma(const float* __restrict__ X, const float* __restrict__ Y,
              float* __restrict__ O, int ldo) {
    // static LDS, manually partitioned so the output restage can alias A/B
    __shared__ __align__(16) char smem[70656];
    unsigned short* Ab  = (unsigned short*)smem;            // [128][136] bf16
    unsigned short* Bb  = (unsigned short*)(smem + 34816);  // [128][136] bf16
    float*          Ol  = (float*)smem;                     // [128][132] f32 (aliases A/B)
    float*          x2s = (float*)(smem + 69632);           // [128]
    float*          y2s = (float*)(smem + 70144);           // [128]

    const int t    = threadIdx.x;
    const int row0 = blockIdx.x * TILE;
    const int col0 = blockIdx.y * TILE;
    const float* xs = X + (size_t)row0 * 128;
    const float* ys = Y + (size_t)col0 * 128;

    // ---- stage: fp32 global -> bf16 LDS (coalesced float4 loads) ----
#pragma unroll
    for (int i = 0; i < 16; ++i) {
        int idx = i * 256 + t;          // float4 index within 128x128 tile
        int r   = idx >> 5;             // 32 float4 per row
        int c   = (idx & 31) * 4;
        float4 a = ((const float4*)xs)[idx];
        float4 b = ((const float4*)ys)[idx];
        us4 av, bv;
        av.x = f2bf(a.x); av.y = f2bf(a.y); av.z = f2bf(a.z); av.w = f2bf(a.w);
        bv.x = f2bf(b.x); bv.y = f2bf(b.y); bv.z = f2bf(b.z); bv.w = f2bf(b.w);
        *(us4*)&Ab[r * APAD + c] = av;
        *(us4*)&Bb[r * APAD + c] = bv;
    }
    __syncthreads();

    // ---- row norms (threads 0-127: x rows, 128-255: y rows) ----
    {
        int r = t & 127;
        const unsigned short* src = (t < 128) ? Ab : Bb;
        float s = 0.f;
#pragma unroll
        for (int c = 0; c < 128; c += 4) {
            us4 v = *(const us4*)&src[r * APAD + c];
            float f0 = bf2f(v.x), f1 = bf2f(v.y), f2 = bf2f(v.z), f3 = bf2f(v.w);
            s += f0 * f0 + f1 * f1 + f2 * f2 + f3 * f3;
        }
        if (t < 128) x2s[r] = s; else y2s[r] = s;
    }
    __syncthreads();

    // ---- MFMA K-loop: C = A * B^T (both tiles stored [row][k]) ----
    const int l  = t & 63;
    const int w  = t >> 6;
    const int wr = (w >> 1) * 64;       // wave row offset
    const int wc = (w & 1) * 64;        // wave col offset
    const int lr = l & 15;
    const int kg = (l >> 4) * 8;        // k sub-offset per 16-lane group

    f32x4 acc[4][4] = {};
#pragma unroll
    for (int k0 = 0; k0 < 128; k0 += 32) {
        bf16x8 af[4], bfr[4];
#pragma unroll
        for (int m = 0; m < 4; ++m)
            af[m] = *(const bf16x8*)&Ab[(wr + m * 16 + lr) * APAD + k0 + kg];
#pragma unroll
        for (int n = 0; n < 4; ++n)
            bfr[n] = *(const bf16x8*)&Bb[(wc + n * 16 + lr) * APAD + k0 + kg];
#pragma unroll
        for (int m = 0; m < 4; ++m)
#pragma unroll
            for (int n = 0; n < 4; ++n)
                acc[m][n] = __builtin_amdgcn_mfma_f32_16x16x32_bf16(
                    af[m], bfr[n], acc[m][n], 0, 0, 0);
    }
    __syncthreads();   // all LDS A/B reads done before aliasing with Ol

    // ---- epilogue: sq = x2+y2-2xy, clamp, exp -> LDS restage ----
#pragma unroll
    for (int m = 0; m < 4; ++m) {
        int rb = wr + m * 16 + (l >> 4) * 4;   // C/D: row = (lane>>4)*4 + reg
#pragma unroll
        for (int n = 0; n < 4; ++n) {
            int cc = wc + n * 16 + lr;          // C/D: col = lane&15
            float y2 = y2s[cc];
            f32x4 v = acc[m][n];
#pragma unroll
            for (int i = 0; i < 4; ++i) {
                float sq = x2s[rb + i] + y2 - 2.f * v[i];
                sq = fmaxf(sq, 0.f);
                Ol[(rb + i) * OPAD + cc] = __expf(-sq);
            }
        }
    }
    __syncthreads();

    // ---- coalesced float4 store of the 128x128 tile ----
#pragma unroll
    for (int i = 0; i < 16; ++i) {
        int idx = i * 256 + t;
        int r   = idx >> 5;
        int c   = (idx & 31) * 4;
        *(float4*)&O[(size_t)(row0 + r) * ldo + col0 + c] =
            *(const float4*)&Ol[r * OPAD + c];
    }
}

extern "C" void kernel_launch(void* const* d_in, const int* in_sizes, int n_in,
                              void* d_out, int out_size, void* d_ws, size_t ws_size,
                              hipStream_t stream) {
    const float* X = (const float*)d_in[0];
    const float* Y = (const float*)d_in[1];
    float* O = (float*)d_out;
    const int N = in_sizes[0] / 128;   // 8192 rows of x
    const int M = in_sizes[1] / 128;   // 8192 rows of y (= output cols)
    dim3 grid(N / TILE, M / TILE);
    rbf_mfma<<<grid, dim3(256), 0, stream>>>(X, Y, O, M);
}

// Round 2
// 314.164 us; speedup vs baseline: 1.0315x; 1.0315x over previous
//
#include <hip/hip_runtime.h>
#include <hip/hip_bf16.h>

typedef __bf16 bf16x8 __attribute__((ext_vector_type(8)));
typedef float f32x4 __attribute__((ext_vector_type(4)));
typedef unsigned short us4 __attribute__((ext_vector_type(4)));

__device__ __forceinline__ unsigned short f2bf(float f) {
    unsigned u = __float_as_uint(f);
    u += 0x7fffu + ((u >> 16) & 1u);   // round-to-nearest-even
    return (unsigned short)(u >> 16);
}

// ---- prep: fp32 -> bf16 (stored with 16B-chunk XOR swizzle) + fp32 row norms ----
// Swizzle: within each 256B row, 16B chunk lc stored at pc = lc ^ (row & 7).
__global__ __launch_bounds__(256)
void rbf_prep(const float* __restrict__ X, const float* __restrict__ Y,
              unsigned short* __restrict__ Xb, unsigned short* __restrict__ Yb,
              float* __restrict__ x2, float* __restrict__ y2) {
    const int b = blockIdx.x;                 // 0..127 -> X, 128..255 -> Y
    const float* src = (b < 128) ? X : Y;
    unsigned short* db = (b < 128) ? Xb : Yb;
    float* dn = (b < 128) ? x2 : y2;
    const int r0 = (b & 127) * 64;            // 64 rows per block (r0 % 8 == 0)
    const int t = threadIdx.x;
    const f32x4* s4 = (const f32x4*)(src + (size_t)r0 * 128);
#pragma unroll
    for (int i = 0; i < 8; ++i) {
        int idx = i * 256 + t;                // float4 index within 64x128 block
        int r = idx >> 5, c4 = idx & 31;      // 32 float4 per row
        f32x4 v = s4[idx];
        us4 o;
        o.x = f2bf(v[0]); o.y = f2bf(v[1]); o.z = f2bf(v[2]); o.w = f2bf(v[3]);
        int pc = (c4 >> 1) ^ (r & 7);         // physical 16B chunk
        *(us4*)&db[(size_t)(r0 + r) * 128 + pc * 8 + (c4 & 1) * 4] = o;
    }
    if (t < 64) {                             // fp32 row norm (L1/L2-hot re-read)
        const f32x4* row = (const f32x4*)(src + (size_t)(r0 + t) * 128);
        float s = 0.f;
#pragma unroll
        for (int c = 0; c < 32; ++c) {
            f32x4 v = row[c];
            s += v[0] * v[0] + v[1] * v[1] + v[2] * v[2] + v[3] * v[3];
        }
        dn[r0 + t] = s;
    }
}

// ---- main: 128x128 tile, global_load_lds stage (linear dest, pre-swizzled src),
//      swizzled ds_read_b128, MFMA, exp epilogue with direct nontemporal stores ----
__global__ __launch_bounds__(256, 2)
void rbf_main(const unsigned short* __restrict__ Xb, const unsigned short* __restrict__ Yb,
              const float* __restrict__ x2, const float* __restrict__ y2,
              float* __restrict__ O, int ldo) {
    __shared__ __align__(16) unsigned short Ab[16384];   // 32 KB [128][128] bf16 (swizzled)
    __shared__ __align__(16) unsigned short Bb[16384];   // 32 KB
    const int t = threadIdx.x, l = t & 63, w = t >> 6;
    const int row0 = blockIdx.x * 128, col0 = blockIdx.y * 128;

    // stage: 16B/lane, wave-uniform LDS base + lane*16 (HW rule), linear copy of
    // the pre-swizzled global layout
    const char* gA = (const char*)(Xb + (size_t)row0 * 128);
    const char* gB = (const char*)(Yb + (size_t)col0 * 128);
#pragma unroll
    for (int j = 0; j < 8; ++j) {
        int base = (w * 8 + j) * 1024;        // 64-chunk group byte offset
        __builtin_amdgcn_global_load_lds(
            (const __attribute__((address_space(1))) void*)(gA + base + l * 16),
            (__attribute__((address_space(3))) void*)((char*)Ab + base), 16, 0, 0);
        __builtin_amdgcn_global_load_lds(
            (const __attribute__((address_space(1))) void*)(gB + base + l * 16),
            (__attribute__((address_space(3))) void*)((char*)Bb + base), 16, 0, 0);
    }

    const int lr = l & 15, q = l >> 4;
    const int wr = (w >> 1) * 64, wc = (w & 1) * 64;

    // norms straight from global (L2-hot); latency hides under the staging drain
    f32x4 x2v[4]; float y2v[4];
#pragma unroll
    for (int m = 0; m < 4; ++m) x2v[m] = *(const f32x4*)&x2[row0 + wr + m * 16 + q * 4];
#pragma unroll
    for (int n = 0; n < 4; ++n) y2v[n] = y2[col0 + wc + n * 16 + lr];

    __syncthreads();

    f32x4 acc[4][4] = {};
#pragma unroll
    for (int k = 0; k < 4; ++k) {             // K-step = 32 elems = 4 chunks
        bf16x8 af[4], bv[4];
#pragma unroll
        for (int m = 0; m < 4; ++m) {
            int R = wr + m * 16 + lr;
            af[m] = *(const bf16x8*)((const char*)Ab + R * 256 + (((k << 2) + q) ^ (R & 7)) * 16);
        }
#pragma unroll
        for (int n = 0; n < 4; ++n) {
            int R = wc + n * 16 + lr;
            bv[n] = *(const bf16x8*)((const char*)Bb + R * 256 + (((k << 2) + q) ^ (R & 7)) * 16);
        }
#pragma unroll
        for (int m = 0; m < 4; ++m)
#pragma unroll
            for (int n = 0; n < 4; ++n)
                acc[m][n] = __builtin_amdgcn_mfma_f32_16x16x32_bf16(af[m], bv[n], acc[m][n], 0, 0, 0);
    }

    // epilogue: sq = x2+y2-2xy -> exp, direct stores from fragment layout
    // (per instruction: 4 x 64B contiguous segments; n-pairs complete 128B lines)
#pragma unroll
    for (int m = 0; m < 4; ++m) {
        int rbase = row0 + wr + m * 16 + q * 4;
#pragma unroll
        for (int n = 0; n < 4; ++n) {
            float* op = &O[(size_t)rbase * ldo + col0 + wc + n * 16 + lr];
            float yv = y2v[n];
#pragma unroll
            for (int i = 0; i < 4; ++i) {
                float sq = x2v[m][i] + yv - 2.0f * acc[m][n][i];
                sq = fmaxf(sq, 0.f);
                __builtin_nontemporal_store(__expf(-sq), op);
                op += ldo;
            }
        }
    }
}

extern "C" void kernel_launch(void* const* d_in, const int* in_sizes, int n_in,
                              void* d_out, int out_size, void* d_ws, size_t ws_size,
                              hipStream_t stream) {
    const float* X = (const float*)d_in[0];
    const float* Y = (const float*)d_in[1];
    float* O = (float*)d_out;
    const int N = in_sizes[0] / 128;          // 8192
    const int M = in_sizes[1] / 128;          // 8192
    unsigned short* Xb = (unsigned short*)d_ws;
    unsigned short* Yb = Xb + (size_t)N * 128;
    float* x2 = (float*)(Yb + (size_t)M * 128);
    float* y2 = x2 + N;
    rbf_prep<<<dim3((N + M) / 64), 256, 0, stream>>>(X, Y, Xb, Yb, x2, y2);
    rbf_main<<<dim3(N / 128, M / 128), 256, 0, stream>>>(Xb, Yb, x2, y2, O, M);
}

// Round 3
// 286.221 us; speedup vs baseline: 1.1322x; 1.0976x over previous
//
#include <hip/hip_runtime.h>
#include <hip/hip_bf16.h>

typedef __bf16 bf16x8 __attribute__((ext_vector_type(8)));
typedef float f32x4 __attribute__((ext_vector_type(4)));
typedef unsigned short us4 __attribute__((ext_vector_type(4)));

__device__ __forceinline__ unsigned short f2bf(float f) {
    unsigned u = __float_as_uint(f);
    u += 0x7fffu + ((u >> 16) & 1u);   // round-to-nearest-even
    return (unsigned short)(u >> 16);
}

// ---- prep: fp32 -> bf16 (stored with 16B-chunk XOR swizzle) + fp32 row norms ----
__global__ __launch_bounds__(256)
void rbf_prep(const float* __restrict__ X, const float* __restrict__ Y,
              unsigned short* __restrict__ Xb, unsigned short* __restrict__ Yb,
              float* __restrict__ x2, float* __restrict__ y2) {
    const int b = blockIdx.x;
    const float* src = (b < 128) ? X : Y;
    unsigned short* db = (b < 128) ? Xb : Yb;
    float* dn = (b < 128) ? x2 : y2;
    const int r0 = (b & 127) * 64;
    const int t = threadIdx.x;
    const f32x4* s4 = (const f32x4*)(src + (size_t)r0 * 128);
#pragma unroll
    for (int i = 0; i < 8; ++i) {
        int idx = i * 256 + t;
        int r = idx >> 5, c4 = idx & 31;
        f32x4 v = s4[idx];
        us4 o;
        o.x = f2bf(v[0]); o.y = f2bf(v[1]); o.z = f2bf(v[2]); o.w = f2bf(v[3]);
        int pc = (c4 >> 1) ^ (r & 7);
        *(us4*)&db[(size_t)(r0 + r) * 128 + pc * 8 + (c4 & 1) * 4] = o;
    }
    if (t < 64) {
        const f32x4* row = (const f32x4*)(src + (size_t)(r0 + t) * 128);
        float s = 0.f;
#pragma unroll
        for (int c = 0; c < 32; ++c) {
            f32x4 v = row[c];
            s += v[0] * v[0] + v[1] * v[1] + v[2] * v[2] + v[3] * v[3];
        }
        dn[r0 + t] = s;
    }
}

// ---- main: stage via global_load_lds, MFMA, exp epilogue -> LDS restage ->
//      fully-coalesced float4 stores (full 128B line coverage, no write-allocate) ----
__global__ __launch_bounds__(256, 2)
void rbf_main(const unsigned short* __restrict__ Xb, const unsigned short* __restrict__ Yb,
              const float* __restrict__ x2, const float* __restrict__ y2,
              float* __restrict__ O, int ldo) {
    __shared__ __align__(16) char smem[65536];
    unsigned short* Ab = (unsigned short*)smem;            // [128][128] bf16 swizzled
    unsigned short* Bb = (unsigned short*)(smem + 32768);
    float*          Ol = (float*)smem;                     // aliases A/B after barrier

    const int t = threadIdx.x, l = t & 63, w = t >> 6;
    const int row0 = blockIdx.x * 128, col0 = blockIdx.y * 128;

    const char* gA = (const char*)(Xb + (size_t)row0 * 128);
    const char* gB = (const char*)(Yb + (size_t)col0 * 128);
#pragma unroll
    for (int j = 0; j < 8; ++j) {
        int base = (w * 8 + j) * 1024;
        __builtin_amdgcn_global_load_lds(
            (const __attribute__((address_space(1))) void*)(gA + base + l * 16),
            (__attribute__((address_space(3))) void*)(smem + base), 16, 0, 0);
        __builtin_amdgcn_global_load_lds(
            (const __attribute__((address_space(1))) void*)(gB + base + l * 16),
            (__attribute__((address_space(3))) void*)(smem + 32768 + base), 16, 0, 0);
    }

    const int lr = l & 15, q = l >> 4;
    const int wr = (w >> 1) * 64, wc = (w & 1) * 64;

    f32x4 x2v[4]; float y2v[4];
#pragma unroll
    for (int m = 0; m < 4; ++m) x2v[m] = *(const f32x4*)&x2[row0 + wr + m * 16 + q * 4];
#pragma unroll
    for (int n = 0; n < 4; ++n) y2v[n] = y2[col0 + wc + n * 16 + lr];

    __syncthreads();

    f32x4 acc[4][4] = {};
#pragma unroll
    for (int k = 0; k < 4; ++k) {
        bf16x8 af[4], bv[4];
#pragma unroll
        for (int m = 0; m < 4; ++m) {
            int R = wr + m * 16 + lr;
            af[m] = *(const bf16x8*)((const char*)Ab + R * 256 + (((k << 2) + q) ^ (R & 7)) * 16);
        }
#pragma unroll
        for (int n = 0; n < 4; ++n) {
            int R = wc + n * 16 + lr;
            bv[n] = *(const bf16x8*)((const char*)Bb + R * 256 + (((k << 2) + q) ^ (R & 7)) * 16);
        }
#pragma unroll
        for (int m = 0; m < 4; ++m)
#pragma unroll
            for (int n = 0; n < 4; ++n)
                acc[m][n] = __builtin_amdgcn_mfma_f32_16x16x32_bf16(af[m], bv[n], acc[m][n], 0, 0, 0);
    }

    __syncthreads();   // all A/B LDS reads complete before aliasing with Ol

    // epilogue: exp -> swizzled LDS restage ([row][chunk pc], pc = (lc&24)|((lc^row)&7))
    // per ds_write instruction: 2-way bank alias only (free)
#pragma unroll
    for (int m = 0; m < 4; ++m) {
        int rloc = wr + m * 16 + q * 4;
#pragma unroll
        for (int n = 0; n < 4; ++n) {
            int col = wc + n * 16 + lr;
            int lc = col >> 2;
            float yv = y2v[n];
#pragma unroll
            for (int i = 0; i < 4; ++i) {
                int row = rloc + i;
                float sq = fmaxf(x2v[m][i] + yv - 2.0f * acc[m][n][i], 0.f);
                int pc = (lc & 24) | ((lc ^ row) & 7);
                Ol[row * 128 + pc * 4 + (col & 3)] = __expf(-sq);
            }
        }
    }
    __syncthreads();

    // fully-coalesced store: each wave instruction writes 1KB contiguous
#pragma unroll
    for (int i = 0; i < 16; ++i) {
        int idx = i * 256 + t;
        int r = idx >> 5, lcc = idx & 31;
        int pc = (lcc & 24) | ((lcc ^ r) & 7);
        f32x4 v = *(const f32x4*)((const char*)Ol + r * 512 + pc * 16);
        *(float4*)&O[(size_t)(row0 + r) * ldo + col0 + lcc * 4] = *(float4*)&v;
    }
}

extern "C" void kernel_launch(void* const* d_in, const int* in_sizes, int n_in,
                              void* d_out, int out_size, void* d_ws, size_t ws_size,
                              hipStream_t stream) {
    const float* X = (const float*)d_in[0];
    const float* Y = (const float*)d_in[1];
    float* O = (float*)d_out;
    const int N = in_sizes[0] / 128;          // 8192
    const int M = in_sizes[1] / 128;          // 8192
    unsigned short* Xb = (unsigned short*)d_ws;
    unsigned short* Yb = Xb + (size_t)N * 128;
    float* x2 = (float*)(Yb + (size_t)M * 128);
    float* y2 = x2 + N;
    rbf_prep<<<dim3((N + M) / 64), 256, 0, stream>>>(X, Y, Xb, Yb, x2, y2);
    rbf_main<<<dim3(N / 128, M / 128), 256, 0, stream>>>(Xb, Yb, x2, y2, O, M);
}

// Round 4
// 284.915 us; speedup vs baseline: 1.1374x; 1.0046x over previous
//
#include <hip/hip_runtime.h>
#include <hip/hip_bf16.h>

typedef __bf16 bf16x8 __attribute__((ext_vector_type(8)));
typedef float f32x4 __attribute__((ext_vector_type(4)));
typedef unsigned short us4 __attribute__((ext_vector_type(4)));

__device__ __forceinline__ unsigned short f2bf(float f) {
    unsigned u = __float_as_uint(f);
    u += 0x7fffu + ((u >> 16) & 1u);   // round-to-nearest-even
    return (unsigned short)(u >> 16);
}

// ---- prep: fp32 -> bf16 (stored with 16B-chunk XOR swizzle) + fp32 row norms ----
__global__ __launch_bounds__(256)
void rbf_prep(const float* __restrict__ X, const float* __restrict__ Y,
              unsigned short* __restrict__ Xb, unsigned short* __restrict__ Yb,
              float* __restrict__ x2, float* __restrict__ y2) {
    const int b = blockIdx.x;
    const float* src = (b < 128) ? X : Y;
    unsigned short* db = (b < 128) ? Xb : Yb;
    float* dn = (b < 128) ? x2 : y2;
    const int r0 = (b & 127) * 64;
    const int t = threadIdx.x;
    const f32x4* s4 = (const f32x4*)(src + (size_t)r0 * 128);
#pragma unroll
    for (int i = 0; i < 8; ++i) {
        int idx = i * 256 + t;
        int r = idx >> 5, c4 = idx & 31;
        f32x4 v = s4[idx];
        us4 o;
        o.x = f2bf(v[0]); o.y = f2bf(v[1]); o.z = f2bf(v[2]); o.w = f2bf(v[3]);
        int pc = (c4 >> 1) ^ (r & 7);
        *(us4*)&db[(size_t)(r0 + r) * 128 + pc * 8 + (c4 & 1) * 4] = o;
    }
    if (t < 64) {
        const f32x4* row = (const f32x4*)(src + (size_t)(r0 + t) * 128);
        float s = 0.f;
#pragma unroll
        for (int c = 0; c < 32; ++c) {
            f32x4 v = row[c];
            s += v[0] * v[0] + v[1] * v[1] + v[2] * v[2] + v[3] * v[3];
        }
        dn[r0 + t] = s;
    }
}

// ---- main: identical to round 3 EXCEPT blockIdx.x now indexes the COLUMN tile,
//      so consecutive/co-resident blocks write one contiguous 4MB row-band ----
__global__ __launch_bounds__(256, 2)
void rbf_main(const unsigned short* __restrict__ Xb, const unsigned short* __restrict__ Yb,
              const float* __restrict__ x2, const float* __restrict__ y2,
              float* __restrict__ O, int ldo) {
    __shared__ __align__(16) char smem[65536];
    unsigned short* Ab = (unsigned short*)smem;            // [128][128] bf16 swizzled
    unsigned short* Bb = (unsigned short*)(smem + 32768);
    float*          Ol = (float*)smem;                     // aliases A/B after barrier

    const int t = threadIdx.x, l = t & 63, w = t >> 6;
    const int col0 = blockIdx.x * 128, row0 = blockIdx.y * 128;   // x = COLUMN tile

    const char* gA = (const char*)(Xb + (size_t)row0 * 128);
    const char* gB = (const char*)(Yb + (size_t)col0 * 128);
#pragma unroll
    for (int j = 0; j < 8; ++j) {
        int base = (w * 8 + j) * 1024;
        __builtin_amdgcn_global_load_lds(
            (const __attribute__((address_space(1))) void*)(gA + base + l * 16),
            (__attribute__((address_space(3))) void*)(smem + base), 16, 0, 0);
        __builtin_amdgcn_global_load_lds(
            (const __attribute__((address_space(1))) void*)(gB + base + l * 16),
            (__attribute__((address_space(3))) void*)(smem + 32768 + base), 16, 0, 0);
    }

    const int lr = l & 15, q = l >> 4;
    const int wr = (w >> 1) * 64, wc = (w & 1) * 64;

    f32x4 x2v[4]; float y2v[4];
#pragma unroll
    for (int m = 0; m < 4; ++m) x2v[m] = *(const f32x4*)&x2[row0 + wr + m * 16 + q * 4];
#pragma unroll
    for (int n = 0; n < 4; ++n) y2v[n] = y2[col0 + wc + n * 16 + lr];

    __syncthreads();

    f32x4 acc[4][4] = {};
#pragma unroll
    for (int k = 0; k < 4; ++k) {
        bf16x8 af[4], bv[4];
#pragma unroll
        for (int m = 0; m < 4; ++m) {
            int R = wr + m * 16 + lr;
            af[m] = *(const bf16x8*)((const char*)Ab + R * 256 + (((k << 2) + q) ^ (R & 7)) * 16);
        }
#pragma unroll
        for (int n = 0; n < 4; ++n) {
            int R = wc + n * 16 + lr;
            bv[n] = *(const bf16x8*)((const char*)Bb + R * 256 + (((k << 2) + q) ^ (R & 7)) * 16);
        }
#pragma unroll
        for (int m = 0; m < 4; ++m)
#pragma unroll
            for (int n = 0; n < 4; ++n)
                acc[m][n] = __builtin_amdgcn_mfma_f32_16x16x32_bf16(af[m], bv[n], acc[m][n], 0, 0, 0);
    }

    __syncthreads();   // all A/B LDS reads complete before aliasing with Ol

    // epilogue: exp -> swizzled LDS restage ([row][chunk pc], pc = (lc&24)|((lc^row)&7))
#pragma unroll
    for (int m = 0; m < 4; ++m) {
        int rloc = wr + m * 16 + q * 4;
#pragma unroll
        for (int n = 0; n < 4; ++n) {
            int col = wc + n * 16 + lr;
            int lc = col >> 2;
            float yv = y2v[n];
#pragma unroll
            for (int i = 0; i < 4; ++i) {
                int row = rloc + i;
                float sq = fmaxf(x2v[m][i] + yv - 2.0f * acc[m][n][i], 0.f);
                int pc = (lc & 24) | ((lc ^ row) & 7);
                Ol[row * 128 + pc * 4 + (col & 3)] = __expf(-sq);
            }
        }
    }
    __syncthreads();

    // fully-coalesced store: each wave instruction writes 1KB contiguous
#pragma unroll
    for (int i = 0; i < 16; ++i) {
        int idx = i * 256 + t;
        int r = idx >> 5, lcc = idx & 31;
        int pc = (lcc & 24) | ((lcc ^ r) & 7);
        f32x4 v = *(const f32x4*)((const char*)Ol + r * 512 + pc * 16);
        *(float4*)&O[(size_t)(row0 + r) * ldo + col0 + lcc * 4] = *(float4*)&v;
    }
}

extern "C" void kernel_launch(void* const* d_in, const int* in_sizes, int n_in,
                              void* d_out, int out_size, void* d_ws, size_t ws_size,
                              hipStream_t stream) {
    const float* X = (const float*)d_in[0];
    const float* Y = (const float*)d_in[1];
    float* O = (float*)d_out;
    const int N = in_sizes[0] / 128;          // 8192
    const int M = in_sizes[1] / 128;          // 8192
    unsigned short* Xb = (unsigned short*)d_ws;
    unsigned short* Yb = Xb + (size_t)N * 128;
    float* x2 = (float*)(Yb + (size_t)M * 128);
    float* y2 = x2 + N;
    rbf_prep<<<dim3((N + M) / 64), 256, 0, stream>>>(X, Y, Xb, Yb, x2, y2);
    // x = column tile (fastest-varying): co-resident blocks write contiguous row-bands
    rbf_main<<<dim3(M / 128, N / 128), 256, 0, stream>>>(Xb, Yb, x2, y2, O, M);
}

// Round 5
// 277.254 us; speedup vs baseline: 1.1688x; 1.0276x over previous
//
#include <hip/hip_runtime.h>
#include <hip/hip_bf16.h>

typedef __bf16 bf16x8 __attribute__((ext_vector_type(8)));
typedef float f32x4 __attribute__((ext_vector_type(4)));
typedef unsigned short us4 __attribute__((ext_vector_type(4)));

__device__ __forceinline__ unsigned short f2bf(float f) {
    unsigned u = __float_as_uint(f);
    u += 0x7fffu + ((u >> 16) & 1u);   // round-to-nearest-even
    return (unsigned short)(u >> 16);
}

// ---- prep: fp32 -> bf16 (stored with 16B-chunk XOR swizzle) + fp32 row norms ----
__global__ __launch_bounds__(256)
void rbf_prep(const float* __restrict__ X, const float* __restrict__ Y,
              unsigned short* __restrict__ Xb, unsigned short* __restrict__ Yb,
              float* __restrict__ x2, float* __restrict__ y2) {
    const int b = blockIdx.x;
    const float* src = (b < 128) ? X : Y;
    unsigned short* db = (b < 128) ? Xb : Yb;
    float* dn = (b < 128) ? x2 : y2;
    const int r0 = (b & 127) * 64;
    const int t = threadIdx.x;
    const f32x4* s4 = (const f32x4*)(src + (size_t)r0 * 128);
#pragma unroll
    for (int i = 0; i < 8; ++i) {
        int idx = i * 256 + t;
        int r = idx >> 5, c4 = idx & 31;
        f32x4 v = s4[idx];
        us4 o;
        o.x = f2bf(v[0]); o.y = f2bf(v[1]); o.z = f2bf(v[2]); o.w = f2bf(v[3]);
        int pc = (c4 >> 1) ^ (r & 7);
        *(us4*)&db[(size_t)(r0 + r) * 128 + pc * 8 + (c4 & 1) * 4] = o;
    }
    if (t < 64) {
        const f32x4* row = (const f32x4*)(src + (size_t)(r0 + t) * 128);
        float s = 0.f;
#pragma unroll
        for (int c = 0; c < 32; ++c) {
            f32x4 v = row[c];
            s += v[0] * v[0] + v[1] * v[1] + v[2] * v[2] + v[3] * v[3];
        }
        dn[r0 + t] = s;
    }
}

// ---- main: 64x128 tile, 48KB LDS -> 3 blocks/CU for store-drain overlap.
//      Same staging / swizzle / restage store path as round 3. ----
__global__ __launch_bounds__(256, 3)
void rbf_main(const unsigned short* __restrict__ Xb, const unsigned short* __restrict__ Yb,
              const float* __restrict__ x2, const float* __restrict__ y2,
              float* __restrict__ O, int ldo) {
    __shared__ __align__(16) char smem[49152];
    unsigned short* Ab = (unsigned short*)smem;            // [64][128] bf16 swizzled, 16KB
    unsigned short* Bb = (unsigned short*)(smem + 16384);  // [128][128] bf16 swizzled, 32KB
    float*          Ol = (float*)smem;                     // [64][128] f32 restage (aliases)

    const int t = threadIdx.x, l = t & 63, w = t >> 6;
    const int col0 = blockIdx.x * 128, row0 = blockIdx.y * 64;

    const char* gA = (const char*)(Xb + (size_t)row0 * 128);   // 16 KB
    const char* gB = (const char*)(Yb + (size_t)col0 * 128);   // 32 KB
#pragma unroll
    for (int j = 0; j < 4; ++j) {
        int base = (w * 4 + j) * 1024;
        __builtin_amdgcn_global_load_lds(
            (const __attribute__((address_space(1))) void*)(gA + base + l * 16),
            (__attribute__((address_space(3))) void*)(smem + base), 16, 0, 0);
    }
#pragma unroll
    for (int j = 0; j < 8; ++j) {
        int base = (w * 8 + j) * 1024;
        __builtin_amdgcn_global_load_lds(
            (const __attribute__((address_space(1))) void*)(gB + base + l * 16),
            (__attribute__((address_space(3))) void*)(smem + 16384 + base), 16, 0, 0);
    }

    const int lr = l & 15, q = l >> 4;
    const int wr = (w >> 1) * 32, wc = (w & 1) * 64;   // 2x2 wave grid, wave tile 32x64

    f32x4 x2v[2]; float y2v[4];
#pragma unroll
    for (int m = 0; m < 2; ++m) x2v[m] = *(const f32x4*)&x2[row0 + wr + m * 16 + q * 4];
#pragma unroll
    for (int n = 0; n < 4; ++n) y2v[n] = y2[col0 + wc + n * 16 + lr];

    __syncthreads();

    f32x4 acc[2][4] = {};
#pragma unroll
    for (int k = 0; k < 4; ++k) {
        bf16x8 af[2], bv[4];
#pragma unroll
        for (int m = 0; m < 2; ++m) {
            int R = wr + m * 16 + lr;                  // local row 0..63
            af[m] = *(const bf16x8*)((const char*)Ab + R * 256 + (((k << 2) + q) ^ (R & 7)) * 16);
        }
#pragma unroll
        for (int n = 0; n < 4; ++n) {
            int R = wc + n * 16 + lr;                  // local col-row 0..127
            bv[n] = *(const bf16x8*)((const char*)Bb + R * 256 + (((k << 2) + q) ^ (R & 7)) * 16);
        }
#pragma unroll
        for (int m = 0; m < 2; ++m)
#pragma unroll
            for (int n = 0; n < 4; ++n)
                acc[m][n] = __builtin_amdgcn_mfma_f32_16x16x32_bf16(af[m], bv[n], acc[m][n], 0, 0, 0);
    }

    __syncthreads();   // all A/B LDS reads complete before aliasing with Ol

    // epilogue: exp -> swizzled LDS restage (pc = (lc&24)|((lc^row)&7)); 2-way banked
#pragma unroll
    for (int m = 0; m < 2; ++m) {
        int rloc = wr + m * 16 + q * 4;
#pragma unroll
        for (int n = 0; n < 4; ++n) {
            int col = wc + n * 16 + lr;
            int lc = col >> 2;
            float yv = y2v[n];
#pragma unroll
            for (int i = 0; i < 4; ++i) {
                int row = rloc + i;
                float sq = fmaxf(x2v[m][i] + yv - 2.0f * acc[m][n][i], 0.f);
                int pc = (lc & 24) | ((lc ^ row) & 7);
                Ol[row * 128 + pc * 4 + (col & 3)] = __expf(-sq);
            }
        }
    }
    __syncthreads();

    // fully-coalesced store: 64 rows x 128 cols, 1KB contiguous per wave-instr
#pragma unroll
    for (int i = 0; i < 8; ++i) {
        int idx = i * 256 + t;
        int r = idx >> 5, lcc = idx & 31;
        int pc = (lcc & 24) | ((lcc ^ r) & 7);
        f32x4 v = *(const f32x4*)((const char*)Ol + r * 512 + pc * 16);
        *(float4*)&O[(size_t)(row0 + r) * ldo + col0 + lcc * 4] = *(float4*)&v;
    }
}

extern "C" void kernel_launch(void* const* d_in, const int* in_sizes, int n_in,
                              void* d_out, int out_size, void* d_ws, size_t ws_size,
                              hipStream_t stream) {
    const float* X = (const float*)d_in[0];
    const float* Y = (const float*)d_in[1];
    float* O = (float*)d_out;
    const int N = in_sizes[0] / 128;          // 8192
    const int M = in_sizes[1] / 128;          // 8192
    unsigned short* Xb = (unsigned short*)d_ws;
    unsigned short* Yb = Xb + (size_t)N * 128;
    float* x2 = (float*)(Yb + (size_t)M * 128);
    float* y2 = x2 + N;
    rbf_prep<<<dim3((N + M) / 64), 256, 0, stream>>>(X, Y, Xb, Yb, x2, y2);
    rbf_main<<<dim3(M / 128, N / 64), 256, 0, stream>>>(Xb, Yb, x2, y2, O, M);
}